// Round 3
// baseline (700.928 us; speedup 1.0000x reference)
//
#include <hip/hip_runtime.h>
#include <hip/hip_fp16.h>
#include <stdint.h>

#define N_NODES 100000
#define N_EDGES 1600000
#define NB_SCAN 391   // ceil(N_NODES/256)

// Round 18. r17 (667 us) post-mortem: 8-edge dwordx4 gathers == r15 perf ->
// agg was never gather-width-bound; it's per-node VALU overhead: 64-lane
// chunk scheme wastes 3/4 lanes at deg~16 and pays a 24-shfl+24-add
// butterfly per node. Changes: (1) agg = 8 lanes/node (lane owns channel
// quad, acc per-lane across all edges -> NO butterfly, NO shfl, no idle
// lanes); 2 edges/iter with depth-1 prefetch. (2) internal h bf16 -> f16:
// cvt+fma fuses to v_fma_mix_f32 (no unpack shifts) and f16 storage error
// < bf16 -> absmax should not rise. (3) k_fuse 32 nodes/block (LDS 24KB,
// occ cap 75%); dense via explicit float4 LDS reads, ascending-k order.
// (4) k_fuse_heads 32 nodes/block, phases lane-parallelized.

__device__ __forceinline__ float bf2f(unsigned short s) {
    return __uint_as_float(((unsigned)s) << 16);
}
__device__ __forceinline__ unsigned short f2bf(float f) {
    unsigned u = __float_as_uint(f);
    u += 0x7fffu + ((u >> 16) & 1u);
    return (unsigned short)(u >> 16);
}
__device__ __forceinline__ unsigned short f2h(float f) {
    union { __half h; unsigned short s; } u;
    u.h = __float2half(f);
    return u.s;
}
template <bool BF16>
__device__ __forceinline__ float LD(const void* p, size_t i) {
    if (BF16) return bf2f(((const unsigned short*)p)[i]);
    return ((const float*)p)[i];
}

// ---------------- dtype detection (proven) ----------------
__global__ void k_detect(const unsigned* __restrict__ xw, int* __restrict__ flag) {
    __shared__ int tot;
    if (threadIdx.x == 0) tot = 0;
    __syncthreads();
    int hit = 0;
    for (int i = threadIdx.x; i < 1024; i += 256) {
        unsigned e = (xw[i] >> 7) & 0xFFu;
        if (e >= 110u && e <= 135u) hit++;
    }
    atomicAdd(&tot, hit);
    __syncthreads();
    if (threadIdx.x == 0) *flag = (tot >= 512) ? 1 : 0;
}

// ---------------- CSR build ----------------

__global__ void k_hist(const int* __restrict__ ei, int* __restrict__ deg) {
    int e = blockIdx.x * 256 + threadIdx.x;
    if (e < N_EDGES) atomicAdd(&deg[ei[N_EDGES + e]], 1);
}

__global__ void k_scan_partial(const int* __restrict__ deg, int* __restrict__ bsum) {
    int t = threadIdx.x;
    int i = blockIdx.x * 256 + t;
    int v = (i < N_NODES) ? deg[i] : 0;
    for (int off = 32; off > 0; off >>= 1) v += __shfl_down(v, off, 64);
    __shared__ int ws4[4];
    if ((t & 63) == 0) ws4[t >> 6] = v;
    __syncthreads();
    if (t == 0) bsum[blockIdx.x] = ws4[0] + ws4[1] + ws4[2] + ws4[3];
}

__global__ void k_scan_mid(const int* __restrict__ bsum, int* __restrict__ boff) {
    __shared__ int s[512];
    int t = threadIdx.x;
    int v = (t < NB_SCAN) ? bsum[t] : 0;
    s[t] = v;
    __syncthreads();
    for (int off = 1; off < 512; off <<= 1) {
        int x = (t >= off) ? s[t - off] : 0;
        __syncthreads();
        s[t] += x;
        __syncthreads();
    }
    if (t < NB_SCAN) boff[t] = s[t] - v;   // exclusive
}

__global__ void k_scan_final(const int* __restrict__ deg, const int* __restrict__ boff,
                             int* __restrict__ row_start, int* __restrict__ cursor) {
    __shared__ int s[256];
    int t = threadIdx.x;
    int i = blockIdx.x * 256 + t;
    int v = (i < N_NODES) ? deg[i] : 0;
    s[t] = v;
    __syncthreads();
    for (int off = 1; off < 256; off <<= 1) {
        int x = (t >= off) ? s[t - off] : 0;
        __syncthreads();
        s[t] += x;
        __syncthreads();
    }
    if (i < N_NODES) {
        int rs = boff[blockIdx.x] + s[t] - v;
        row_start[i] = rs;
        cursor[i] = rs;
    }
}

// ---------------- CSR scatter: ONE 16B packed write per edge ----------------

template <bool BF>
__device__ __forceinline__ void scatter_body(const int* __restrict__ ei,
                                             const void* __restrict__ ea,
                                             int* __restrict__ cursor,
                                             uint4* __restrict__ csr_edge) {
    int e = blockIdx.x * 256 + threadIdx.x;   // grid exact: 6250*256 = 1.6M
    int s = ei[e];
    int d = ei[N_EDGES + e];
    float a0 = LD<BF>(ea, (size_t)e * 2);
    float a1 = LD<BF>(ea, (size_t)e * 2 + 1);
    int slot = atomicAdd(&cursor[d], 1);
    csr_edge[slot] = make_uint4((unsigned)s, __float_as_uint(a0), __float_as_uint(a1), 0u);
}

__global__ void k_scatter(const int* __restrict__ flag, const int* ei, const void* ea,
                          int* cursor, uint4* csr_edge) {
    if (*flag) scatter_body<true>(ei, ea, cursor, csr_edge);
    else       scatter_body<false>(ei, ea, cursor, csr_edge);
}

// ---------------- edge-MLP pass: slot-ordered, fully coalesced ----------------

template <bool BF>
__device__ __forceinline__ void ew_body(const uint4* __restrict__ csr_edge,
                                        const void* ew1, const void* eb1,
                                        const void* ew2, const void* eb2,
                                        int* __restrict__ csr_src,
                                        float* __restrict__ ew4,
                                        float (*w1)[2][16], float (*b1)[16],
                                        float (*w2)[16], float* b2) {
    int t = threadIdx.x;
    if (t < 128) ((float*)w1)[t] = LD<BF>(ew1, t);
    else if (t < 192) ((float*)b1)[t - 128] = LD<BF>(eb1, t - 128);
    else ((float*)w2)[t - 192] = LD<BF>(ew2, t - 192);
    if (t < 4) b2[t] = LD<BF>(eb2, t);
    __syncthreads();

    int e = blockIdx.x * 256 + t;   // grid exact: 6250*256 = 1.6M
    uint4 u = csr_edge[e];
    csr_src[e] = (int)u.x;
    float a0 = __uint_as_float(u.y);
    float a1 = __uint_as_float(u.z);
    #pragma unroll
    for (int l = 0; l < 4; l++) {
        float z = b2[l];
        #pragma unroll
        for (int q = 0; q < 16; q++) {
            float hj = fmaf(a0, w1[l][0][q], fmaf(a1, w1[l][1][q], b1[l][q]));
            z = fmaf(fmaxf(hj, 0.f), w2[l][q], z);
        }
        ew4[(size_t)l * N_EDGES + e] = 1.f / (1.f + expf(-z));
    }
}

__global__ void k_ew(const int* __restrict__ flag, const uint4* __restrict__ csr_edge,
                     const void* ew1, const void* eb1, const void* ew2, const void* eb2,
                     int* csr_src, float* ew4) {
    __shared__ float w1[4][2][16], b1[4][16], w2[4][16], b2[4];
    if (*flag) ew_body<true>(csr_edge, ew1, eb1, ew2, eb2, csr_src, ew4, w1, b1, w2, b2);
    else       ew_body<false>(csr_edge, ew1, eb1, ew2, eb2, csr_src, ew4, w1, b1, w2, b2);
}

// ---------------- layer 0 dense ----------------

template <bool BF>
__device__ __forceinline__ void dense0_body(const void* __restrict__ x,
                                            const void* __restrict__ W,
                                            const void* __restrict__ b,
                                            unsigned short* __restrict__ h,
                                            float* Wl, float (*xl)[32]) {
    int t = threadIdx.x, w = t >> 6, lane = t & 63;
    for (int i = t; i < 32 * 64; i += 256) Wl[i] = LD<BF>(W, i);
    int v0 = blockIdx.x * 16 + w * 4;
    if (lane < 32) {
        #pragma unroll
        for (int n = 0; n < 4; n++)
            xl[w * 4 + n][lane] = LD<BF>(x, (size_t)(v0 + n) * 32 + lane);
    }
    __syncthreads();
    float bias = LD<BF>(b, lane);
    float a0 = bias, a1 = bias, a2 = bias, a3 = bias;
    #pragma unroll 8
    for (int k = 0; k < 32; k++) {
        float wv = Wl[k * 64 + lane];
        a0 = fmaf(xl[w * 4 + 0][k], wv, a0);
        a1 = fmaf(xl[w * 4 + 1][k], wv, a1);
        a2 = fmaf(xl[w * 4 + 2][k], wv, a2);
        a3 = fmaf(xl[w * 4 + 3][k], wv, a3);
    }
    h[(size_t)(v0 + 0) * 64 + lane] = f2h(a0);
    h[(size_t)(v0 + 1) * 64 + lane] = f2h(a1);
    h[(size_t)(v0 + 2) * 64 + lane] = f2h(a2);
    h[(size_t)(v0 + 3) * 64 + lane] = f2h(a3);
}

__global__ void k_dense0(const int* __restrict__ flag, const void* x, const void* W,
                         const void* b, unsigned short* h) {
    __shared__ float Wl[32 * 64];
    __shared__ float xl[16][32];
    if (*flag) dense0_body<true>(x, W, b, h, Wl, xl);
    else       dense0_body<false>(x, W, b, h, Wl, xl);
}

// ---------------- aggregation: 8 lanes per node, per-lane accumulators ------
// h rows = 64 f16 ch = 8 x uint4. Group g = 8 lanes owns one node; lane
// carries channel quad c = lane&7 (ch 8c..8c+7, one uint4). Accumulators
// stay per-lane for the whole node -> no butterfly, no shfl, no idle lanes.
// 2 edges per iteration, next pair prefetched (depth-1 pipeline).
// __half2float + fmaf fuses to v_fma_mix_f32 (no unpack shifts).

__device__ __forceinline__ void agg_group(int st, int d,
                                          const int* __restrict__ csr_src,
                                          const float* __restrict__ ew,
                                          const uint4* __restrict__ hu4,
                                          int c, float* acc) {
    #pragma unroll
    for (int k = 0; k < 8; k++) acc[k] = 0.f;
    int rem = d, p = st;
    int i0 = 0, i1 = 0;
    float e0 = 0.f, e1 = 0.f;
    if (rem > 0) { i0 = csr_src[p]; e0 = ew[p]; }
    if (rem > 1) { i1 = csr_src[p + 1]; e1 = ew[p + 1]; }
    while (rem > 0) {
        int n0 = 0, n1 = 0;
        float f0 = 0.f, f1 = 0.f;
        if (rem > 2) { n0 = csr_src[p + 2]; f0 = ew[p + 2]; }
        if (rem > 3) { n1 = csr_src[p + 3]; f1 = ew[p + 3]; }
        union { uint4 u; __half h[8]; } H0, H1;
        H0.u = hu4[(size_t)i0 * 8 + c];
        H1.u = hu4[(size_t)i1 * 8 + c];
        #pragma unroll
        for (int k = 0; k < 8; k++) acc[k] = fmaf(e0, __half2float(H0.h[k]), acc[k]);
        #pragma unroll
        for (int k = 0; k < 8; k++) acc[k] = fmaf(e1, __half2float(H1.h[k]), acc[k]);
        i0 = n0; e0 = f0; i1 = n1; e1 = f1;
        p += 2; rem -= 2;
    }
}

// ---------------- fused: x = relu(agg(h_in)); h_out = x @ W + b ----------------
// 32 nodes/block (4 waves x 8 groups x 1 node); LDS 24KB -> 6 blocks/CU

template <bool BF>
__device__ __forceinline__ void fuse_body(const int* row_start, const int* deg,
                                          const int* __restrict__ csr_src,
                                          const float* __restrict__ ew,
                                          const uint4* __restrict__ hu4,
                                          const void* W, int Woff, const void* b, int boff,
                                          unsigned short* h_out,
                                          float* Wl, float (*xs)[64]) {
    int t = threadIdx.x, w = t >> 6, lane = t & 63;
    int g = lane >> 3, c = lane & 7;
    for (int i = t; i < 64 * 64; i += 256) Wl[i] = LD<BF>(W, Woff + i);

    int v = blockIdx.x * 32 + w * 8 + g;   // grid exact: 3125*32 = 100000
    float acc[8];
    agg_group(row_start[v], deg[v], csr_src, ew, hu4, c, acc);
    int row = w * 8 + g;
    *(float4*)&xs[row][c * 8] = make_float4(fmaxf(acc[0], 0.f), fmaxf(acc[1], 0.f),
                                            fmaxf(acc[2], 0.f), fmaxf(acc[3], 0.f));
    *(float4*)&xs[row][c * 8 + 4] = make_float4(fmaxf(acc[4], 0.f), fmaxf(acc[5], 0.f),
                                                fmaxf(acc[6], 0.f), fmaxf(acc[7], 0.f));
    __syncthreads();

    float bias = LD<BF>(b, boff + lane);
    float a[8];
    #pragma unroll
    for (int n = 0; n < 8; n++) a[n] = bias;
    for (int k = 0; k < 64; k += 4) {
        float wv0 = Wl[(k + 0) * 64 + lane];
        float wv1 = Wl[(k + 1) * 64 + lane];
        float wv2 = Wl[(k + 2) * 64 + lane];
        float wv3 = Wl[(k + 3) * 64 + lane];
        #pragma unroll
        for (int n = 0; n < 8; n++) {
            float4 xv = *(const float4*)&xs[w * 8 + n][k];
            a[n] = fmaf(xv.x, wv0, a[n]);
            a[n] = fmaf(xv.y, wv1, a[n]);
            a[n] = fmaf(xv.z, wv2, a[n]);
            a[n] = fmaf(xv.w, wv3, a[n]);
        }
    }
    int v0 = blockIdx.x * 32 + w * 8;
    #pragma unroll
    for (int n = 0; n < 8; n++)
        h_out[(size_t)(v0 + n) * 64 + lane] = f2h(a[n]);
}

__global__ void k_fuse(const int* __restrict__ flag,
                       const int* row_start, const int* deg,
                       const int* __restrict__ csr_src, const float* __restrict__ ew,
                       const void* hu,
                       const void* W, int Woff, const void* b, int boff,
                       unsigned short* h_out) {
    __shared__ float Wl[64 * 64];
    __shared__ float xs[32][64];
    if (*flag)
        fuse_body<true>(row_start, deg, csr_src, ew, (const uint4*)hu,
                        W, Woff, b, boff, h_out, Wl, xs);
    else
        fuse_body<false>(row_start, deg, csr_src, ew, (const uint4*)hu,
                         W, Woff, b, boff, h_out, Wl, xs);
}

// ---------------- fused final: x3 = relu(agg(h3)); heads -> out ---------------
// 32 nodes/block (4 waves x 8 groups x 1 node); LDS ~37.6KB -> 4 blocks/CU

template <bool BF>
__device__ __forceinline__ void fuse_heads_body(
        const int* row_start, const int* deg,
        const int* __restrict__ csr_src, const float* __restrict__ ew,
        const uint4* __restrict__ hu4,
        const void* rh1w, const void* rh1b, const void* rh2w, const void* rh2b,
        const void* meanw, const void* meanb, const void* stdw, const void* stdb,
        const void* cls1w, const void* cls1b, const void* cls2w, const void* cls2b,
        void* __restrict__ out,
        float* s_rh1, float* s_cls1, float* s_rh2, float* s_cls2,
        float* s_rh1b, float* s_cls1b, float* s_rh2b, float* s_mw, float* s_sw,
        float* s_c2b, float* s_msb,
        float (*xs)[64], float (*r1)[32], float (*c1h)[32], float (*r2)[16]) {
    int t = threadIdx.x, w = t >> 6, lane = t & 63;
    for (int i = t; i < 2048; i += 256) { s_rh1[i] = LD<BF>(rh1w, i); s_cls1[i] = LD<BF>(cls1w, i); }
    for (int i = t; i < 512; i += 256) s_rh2[i] = LD<BF>(rh2w, i);
    if (t < 64) s_cls2[t] = LD<BF>(cls2w, t);
    if (t < 32) { s_rh1b[t] = LD<BF>(rh1b, t); s_cls1b[t] = LD<BF>(cls1b, t); }
    else if (t < 48) { int i = t - 32; s_rh2b[i] = LD<BF>(rh2b, i); s_mw[i] = LD<BF>(meanw, i); s_sw[i] = LD<BF>(stdw, i); }
    else if (t == 48) { s_msb[0] = LD<BF>(meanb, 0); s_msb[1] = LD<BF>(stdb, 0); }
    else if (t == 49) { s_c2b[0] = LD<BF>(cls2b, 0); s_c2b[1] = LD<BF>(cls2b, 1); }

    int g = lane >> 3, c = lane & 7;
    int v = blockIdx.x * 32 + w * 8 + g;   // grid exact: 3125*32 = 100000
    float acc[8];
    agg_group(row_start[v], deg[v], csr_src, ew, hu4, c, acc);
    int row = w * 8 + g;
    *(float4*)&xs[row][c * 8] = make_float4(fmaxf(acc[0], 0.f), fmaxf(acc[1], 0.f),
                                            fmaxf(acc[2], 0.f), fmaxf(acc[3], 0.f));
    *(float4*)&xs[row][c * 8 + 4] = make_float4(fmaxf(acc[4], 0.f), fmaxf(acc[5], 0.f),
                                                fmaxf(acc[6], 0.f), fmaxf(acc[7], 0.f));
    __syncthreads();

    // phase1: r1 = relu(xs @ rh1w + b), c1h = relu(xs @ cls1w + b)
    int cc = lane & 31;
    const float* Wp = (lane < 32) ? s_rh1 : s_cls1;
    float bias1 = (lane < 32) ? s_rh1b[cc] : s_cls1b[cc];
    #pragma unroll 2
    for (int n = 0; n < 8; n++) {
        int r = w * 8 + n;
        float a = bias1;
        for (int k = 0; k < 64; k += 4) {
            float4 xv = *(const float4*)&xs[r][k];
            a = fmaf(xv.x, Wp[(k + 0) * 32 + cc], a);
            a = fmaf(xv.y, Wp[(k + 1) * 32 + cc], a);
            a = fmaf(xv.z, Wp[(k + 2) * 32 + cc], a);
            a = fmaf(xv.w, Wp[(k + 3) * 32 + cc], a);
        }
        a = fmaxf(a, 0.f);
        if (lane < 32) r1[r][cc] = a; else c1h[r][cc] = a;
    }
    __syncthreads();

    // phase2: r2 = relu(r1 @ rh2w + b) -- 4 nodes in parallel (16 lanes each)
    {
        int q = lane >> 4, j = lane & 15;
        #pragma unroll
        for (int hh = 0; hh < 2; hh++) {
            int r = w * 8 + hh * 4 + q;
            float a = s_rh2b[j];
            #pragma unroll
            for (int k = 0; k < 32; k++) a = fmaf(r1[r][k], s_rh2[k * 16 + j], a);
            r2[r][j] = fmaxf(a, 0.f);
        }
    }
    __syncthreads();

    // phase3: heads -- 8 nodes x 8 lanes (j=0 mean, j=1 std, j=2,3 cls)
    {
        int r3 = w * 8 + (lane >> 3);
        int vv = blockIdx.x * 32 + r3;
        int j3 = lane & 7;
        if (j3 == 0) {
            float m = s_msb[0];
            #pragma unroll
            for (int k = 0; k < 16; k++) m = fmaf(r2[r3][k], s_mw[k], m);
            if (BF) ((unsigned short*)out)[vv] = f2bf(m); else ((float*)out)[vv] = m;
        } else if (j3 == 1) {
            float sv = s_msb[1];
            #pragma unroll
            for (int k = 0; k < 16; k++) sv = fmaf(r2[r3][k], s_sw[k], sv);
            float sp = fmaxf(sv, 0.f) + log1pf(expf(-fabsf(sv)));   // stable softplus
            if (BF) ((unsigned short*)out)[N_NODES + vv] = f2bf(sp); else ((float*)out)[N_NODES + vv] = sp;
        } else if (j3 < 4) {
            int jj = j3 - 2;
            float a = s_c2b[jj];
            #pragma unroll
            for (int k = 0; k < 32; k++) a = fmaf(c1h[r3][k], s_cls2[k * 2 + jj], a);
            size_t pos = (size_t)2 * N_NODES + (size_t)vv * 2 + jj;
            if (BF) ((unsigned short*)out)[pos] = f2bf(a); else ((float*)out)[pos] = a;
        }
    }
}

__global__ void k_fuse_heads(const int* __restrict__ flag,
                             const int* row_start, const int* deg,
                             const int* __restrict__ csr_src, const float* __restrict__ ew,
                             const void* hu,
                             const void* rh1w, const void* rh1b, const void* rh2w, const void* rh2b,
                             const void* meanw, const void* meanb, const void* stdw, const void* stdb,
                             const void* cls1w, const void* cls1b, const void* cls2w, const void* cls2b,
                             void* out) {
    __shared__ float s_rh1[64 * 32], s_cls1[64 * 32], s_rh2[32 * 16], s_cls2[32 * 2];
    __shared__ float s_rh1b[32], s_cls1b[32], s_rh2b[16], s_mw[16], s_sw[16], s_c2b[2], s_msb[2];
    __shared__ float xs[32][64], r1[32][32], c1h[32][32], r2[32][16];
    if (*flag)
        fuse_heads_body<true>(row_start, deg, csr_src, ew, (const uint4*)hu,
                              rh1w, rh1b, rh2w, rh2b, meanw, meanb, stdw, stdb,
                              cls1w, cls1b, cls2w, cls2b, out,
                              s_rh1, s_cls1, s_rh2, s_cls2, s_rh1b, s_cls1b, s_rh2b,
                              s_mw, s_sw, s_c2b, s_msb, xs, r1, c1h, r2);
    else
        fuse_heads_body<false>(row_start, deg, csr_src, ew, (const uint4*)hu,
                               rh1w, rh1b, rh2w, rh2b, meanw, meanb, stdw, stdb,
                               cls1w, cls1b, cls2w, cls2b, out,
                               s_rh1, s_cls1, s_rh2, s_cls2, s_rh1b, s_cls1b, s_rh2b,
                               s_mw, s_sw, s_c2b, s_msb, xs, r1, c1h, r2);
}

// ---------------- launch ----------------

extern "C" void kernel_launch(void* const* d_in, const int* in_sizes, int n_in,
                              void* d_out, int out_size, void* d_ws, size_t ws_size,
                              hipStream_t stream) {
    const void* x_in  = d_in[0];
    const int* ei     = (const int*)d_in[1];
    const void* ea    = d_in[2];
    const void* W0    = d_in[3];
    const void* b0    = d_in[4];
    const void* Ws    = d_in[5];
    const void* bs    = d_in[6];
    const void* ew1   = d_in[7];
    const void* eb1   = d_in[8];
    const void* ew2   = d_in[9];
    const void* eb2   = d_in[10];
    const void* rh1w  = d_in[11];
    const void* rh1b  = d_in[12];
    const void* rh2w  = d_in[13];
    const void* rh2b  = d_in[14];
    const void* meanw = d_in[15];
    const void* meanb = d_in[16];
    const void* stdw  = d_in[17];
    const void* stdb  = d_in[18];
    const void* cls1w = d_in[19];
    const void* cls1b = d_in[20];
    const void* cls2w = d_in[21];
    const void* cls2b = d_in[22];

    char* wsp = (char*)d_ws;
    auto alloc = [&](size_t bytes) -> char* {
        char* p = wsp;
        wsp += (bytes + 255) & ~(size_t)255;
        return p;
    };
    // footprint ~59 MB (< 78.2 MB proven):
    //   csr_edge (25.6 MB) is dead after k_ew -> aliased with hA+hB (12.8+12.8)
    int* flag       = (int*)alloc(4);
    int* deg        = (int*)alloc((size_t)N_NODES * 4);
    int* row_start  = (int*)alloc((size_t)N_NODES * 4);
    int* cursor     = (int*)alloc((size_t)N_NODES * 4);
    int* bsum       = (int*)alloc((size_t)NB_SCAN * 4);
    int* boff       = (int*)alloc((size_t)NB_SCAN * 4);
    int* csr_src    = (int*)alloc((size_t)N_EDGES * 4);
    float* ew4      = (float*)alloc((size_t)4 * N_EDGES * 4);
    char* hreg      = alloc((size_t)N_EDGES * 16);       // union region, 25.6 MB
    uint4* csr_edge = (uint4*)hreg;
    unsigned short* hA = (unsigned short*)hreg;
    unsigned short* hB = (unsigned short*)(hreg + (size_t)N_NODES * 64 * 2);

    k_detect<<<1, 256, 0, stream>>>((const unsigned*)x_in, flag);
    hipMemsetAsync(deg, 0, (size_t)N_NODES * 4, stream);
    k_hist<<<6250, 256, 0, stream>>>(ei, deg);
    k_scan_partial<<<NB_SCAN, 256, 0, stream>>>(deg, bsum);
    k_scan_mid<<<1, 512, 0, stream>>>(bsum, boff);
    k_scan_final<<<NB_SCAN, 256, 0, stream>>>(deg, boff, row_start, cursor);
    k_scatter<<<6250, 256, 0, stream>>>(flag, ei, ea, cursor, csr_edge);
    k_ew<<<6250, 256, 0, stream>>>(flag, csr_edge, ew1, eb1, ew2, eb2, csr_src, ew4);

    // h0 = x_in @ W0 + b0   (hA clobbers csr_edge region -- dead after k_ew)
    k_dense0<<<6250, 256, 0, stream>>>(flag, x_in, W0, b0, hA);

    unsigned short* hin = hA;
    unsigned short* hout = hB;
    for (int l = 0; l < 3; l++) {
        k_fuse<<<3125, 256, 0, stream>>>(flag, row_start, deg, csr_src,
                                         ew4 + (size_t)l * N_EDGES, hin,
                                         Ws, l * 64 * 64, bs, l * 64, hout);
        unsigned short* tmp = hin; hin = hout; hout = tmp;
    }
    k_fuse_heads<<<3125, 256, 0, stream>>>(flag, row_start, deg, csr_src,
                                           ew4 + (size_t)3 * N_EDGES, hin,
                                           rh1w, rh1b, rh2w, rh2b, meanw, meanb,
                                           stdw, stdb, cls1w, cls1b, cls2w, cls2b,
                                           d_out);
}

// Round 4
// 596.397 us; speedup vs baseline: 1.1753x; 1.1753x over previous
//
#include <hip/hip_runtime.h>
#include <stdint.h>

#define N_NODES 100000
#define N_EDGES 1600000
#define NB_SCAN 391   // ceil(N_NODES/256)

// Round 19. r18 (700 us) post-mortem: union{uint4,__half[8]} type-pun defeated
// SROA -> unions in scratch -> 436MB scratch WRITE + L2 thrash (FETCH 457MB).
// The per-lane-acc idea was never really tested. r19 = r17 base (667us,
// proven) with ONLY the agg replaced: 16 lanes/node (wave = 4 groups), lane
// owns channel quad via one uint2 gather (group reads 128B/row contiguous),
// scalar per-lane accumulators across all edges -> NO butterfly, NO shfl.
// idx/ew read per-group (same addr across 16 lanes -> HW broadcast), 2
// edges/iter, depth-1 scalar prefetch. No unions/arrays/runtime indexing.
// k_fuse 16 nodes/block (LDS 20KB); dense reads xs as lane-uniform float4
// (LDS broadcast). k_fuse_heads: r17 phases verbatim, agg swapped.

__device__ __forceinline__ float bf2f(unsigned short s) {
    return __uint_as_float(((unsigned)s) << 16);
}
__device__ __forceinline__ unsigned short f2bf(float f) {
    unsigned u = __float_as_uint(f);
    u += 0x7fffu + ((u >> 16) & 1u);
    return (unsigned short)(u >> 16);
}
template <bool BF16>
__device__ __forceinline__ float LD(const void* p, size_t i) {
    if (BF16) return bf2f(((const unsigned short*)p)[i]);
    return ((const float*)p)[i];
}

// ---------------- dtype detection (proven) ----------------
__global__ void k_detect(const unsigned* __restrict__ xw, int* __restrict__ flag) {
    __shared__ int tot;
    if (threadIdx.x == 0) tot = 0;
    __syncthreads();
    int hit = 0;
    for (int i = threadIdx.x; i < 1024; i += 256) {
        unsigned e = (xw[i] >> 7) & 0xFFu;
        if (e >= 110u && e <= 135u) hit++;
    }
    atomicAdd(&tot, hit);
    __syncthreads();
    if (threadIdx.x == 0) *flag = (tot >= 512) ? 1 : 0;
}

// ---------------- CSR build ----------------

__global__ void k_hist(const int* __restrict__ ei, int* __restrict__ deg) {
    int e = blockIdx.x * 256 + threadIdx.x;
    if (e < N_EDGES) atomicAdd(&deg[ei[N_EDGES + e]], 1);
}

__global__ void k_scan_partial(const int* __restrict__ deg, int* __restrict__ bsum) {
    int t = threadIdx.x;
    int i = blockIdx.x * 256 + t;
    int v = (i < N_NODES) ? deg[i] : 0;
    for (int off = 32; off > 0; off >>= 1) v += __shfl_down(v, off, 64);
    __shared__ int ws4[4];
    if ((t & 63) == 0) ws4[t >> 6] = v;
    __syncthreads();
    if (t == 0) bsum[blockIdx.x] = ws4[0] + ws4[1] + ws4[2] + ws4[3];
}

__global__ void k_scan_mid(const int* __restrict__ bsum, int* __restrict__ boff) {
    __shared__ int s[512];
    int t = threadIdx.x;
    int v = (t < NB_SCAN) ? bsum[t] : 0;
    s[t] = v;
    __syncthreads();
    for (int off = 1; off < 512; off <<= 1) {
        int x = (t >= off) ? s[t - off] : 0;
        __syncthreads();
        s[t] += x;
        __syncthreads();
    }
    if (t < NB_SCAN) boff[t] = s[t] - v;   // exclusive
}

__global__ void k_scan_final(const int* __restrict__ deg, const int* __restrict__ boff,
                             int* __restrict__ row_start, int* __restrict__ cursor) {
    __shared__ int s[256];
    int t = threadIdx.x;
    int i = blockIdx.x * 256 + t;
    int v = (i < N_NODES) ? deg[i] : 0;
    s[t] = v;
    __syncthreads();
    for (int off = 1; off < 256; off <<= 1) {
        int x = (t >= off) ? s[t - off] : 0;
        __syncthreads();
        s[t] += x;
        __syncthreads();
    }
    if (i < N_NODES) {
        int rs = boff[blockIdx.x] + s[t] - v;
        row_start[i] = rs;
        cursor[i] = rs;
    }
}

// ---------------- CSR scatter: ONE 16B packed write per edge ----------------

template <bool BF>
__device__ __forceinline__ void scatter_body(const int* __restrict__ ei,
                                             const void* __restrict__ ea,
                                             int* __restrict__ cursor,
                                             uint4* __restrict__ csr_edge) {
    int e = blockIdx.x * 256 + threadIdx.x;   // grid exact: 6250*256 = 1.6M
    int s = ei[e];
    int d = ei[N_EDGES + e];
    float a0 = LD<BF>(ea, (size_t)e * 2);
    float a1 = LD<BF>(ea, (size_t)e * 2 + 1);
    int slot = atomicAdd(&cursor[d], 1);
    csr_edge[slot] = make_uint4((unsigned)s, __float_as_uint(a0), __float_as_uint(a1), 0u);
}

__global__ void k_scatter(const int* __restrict__ flag, const int* ei, const void* ea,
                          int* cursor, uint4* csr_edge) {
    if (*flag) scatter_body<true>(ei, ea, cursor, csr_edge);
    else       scatter_body<false>(ei, ea, cursor, csr_edge);
}

// ---------------- edge-MLP pass: slot-ordered, fully coalesced ----------------

template <bool BF>
__device__ __forceinline__ void ew_body(const uint4* __restrict__ csr_edge,
                                        const void* ew1, const void* eb1,
                                        const void* ew2, const void* eb2,
                                        int* __restrict__ csr_src,
                                        float* __restrict__ ew4,
                                        float (*w1)[2][16], float (*b1)[16],
                                        float (*w2)[16], float* b2) {
    int t = threadIdx.x;
    if (t < 128) ((float*)w1)[t] = LD<BF>(ew1, t);
    else if (t < 192) ((float*)b1)[t - 128] = LD<BF>(eb1, t - 128);
    else ((float*)w2)[t - 192] = LD<BF>(ew2, t - 192);
    if (t < 4) b2[t] = LD<BF>(eb2, t);
    __syncthreads();

    int e = blockIdx.x * 256 + t;   // grid exact: 6250*256 = 1.6M
    uint4 u = csr_edge[e];
    csr_src[e] = (int)u.x;
    float a0 = __uint_as_float(u.y);
    float a1 = __uint_as_float(u.z);
    #pragma unroll
    for (int l = 0; l < 4; l++) {
        float z = b2[l];
        #pragma unroll
        for (int q = 0; q < 16; q++) {
            float hj = fmaf(a0, w1[l][0][q], fmaf(a1, w1[l][1][q], b1[l][q]));
            z = fmaf(fmaxf(hj, 0.f), w2[l][q], z);
        }
        ew4[(size_t)l * N_EDGES + e] = 1.f / (1.f + expf(-z));
    }
}

__global__ void k_ew(const int* __restrict__ flag, const uint4* __restrict__ csr_edge,
                     const void* ew1, const void* eb1, const void* ew2, const void* eb2,
                     int* csr_src, float* ew4) {
    __shared__ float w1[4][2][16], b1[4][16], w2[4][16], b2[4];
    if (*flag) ew_body<true>(csr_edge, ew1, eb1, ew2, eb2, csr_src, ew4, w1, b1, w2, b2);
    else       ew_body<false>(csr_edge, ew1, eb1, ew2, eb2, csr_src, ew4, w1, b1, w2, b2);
}

// ---------------- layer 0 dense ----------------

template <bool BF>
__device__ __forceinline__ void dense0_body(const void* __restrict__ x,
                                            const void* __restrict__ W,
                                            const void* __restrict__ b,
                                            unsigned short* __restrict__ h,
                                            float* Wl, float (*xl)[32]) {
    int t = threadIdx.x, w = t >> 6, lane = t & 63;
    for (int i = t; i < 32 * 64; i += 256) Wl[i] = LD<BF>(W, i);
    int v0 = blockIdx.x * 16 + w * 4;
    if (lane < 32) {
        #pragma unroll
        for (int n = 0; n < 4; n++)
            xl[w * 4 + n][lane] = LD<BF>(x, (size_t)(v0 + n) * 32 + lane);
    }
    __syncthreads();
    float bias = LD<BF>(b, lane);
    float a0 = bias, a1 = bias, a2 = bias, a3 = bias;
    #pragma unroll 8
    for (int k = 0; k < 32; k++) {
        float wv = Wl[k * 64 + lane];
        a0 = fmaf(xl[w * 4 + 0][k], wv, a0);
        a1 = fmaf(xl[w * 4 + 1][k], wv, a1);
        a2 = fmaf(xl[w * 4 + 2][k], wv, a2);
        a3 = fmaf(xl[w * 4 + 3][k], wv, a3);
    }
    h[(size_t)(v0 + 0) * 64 + lane] = f2bf(a0);
    h[(size_t)(v0 + 1) * 64 + lane] = f2bf(a1);
    h[(size_t)(v0 + 2) * 64 + lane] = f2bf(a2);
    h[(size_t)(v0 + 3) * 64 + lane] = f2bf(a3);
}

__global__ void k_dense0(const int* __restrict__ flag, const void* x, const void* W,
                         const void* b, unsigned short* h) {
    __shared__ float Wl[32 * 64];
    __shared__ float xl[16][32];
    if (*flag) dense0_body<true>(x, W, b, h, Wl, xl);
    else       dense0_body<false>(x, W, b, h, Wl, xl);
}

// ---------------- aggregation: 16 lanes/node, per-lane scalar accumulators --
// h rows = 64 bf16 = 16 uint2. Group of 16 lanes owns one node; lane j owns
// channel quad 4j..4j+3 (one uint2 = 8B gather; group reads 128B/row
// contiguous). Accumulators are scalars held per-lane across all edges ->
// no butterfly, no shfl. idx/ew loads: all 16 lanes of a group read the
// same address (HW broadcast, L1-resident sequential stream). 2 edges per
// iteration, depth-1 scalar prefetch. No unions/arrays (scratch-safe).

__device__ __forceinline__ float4 agg16(int p, int d,
                                        const int* __restrict__ csr_src,
                                        const float* __restrict__ ew,
                                        const uint2* __restrict__ hu2,
                                        int j) {
    float a0 = 0.f, a1 = 0.f, a2 = 0.f, a3 = 0.f;
    int i0 = 0, i1 = 0;
    float e0 = 0.f, e1 = 0.f;
    if (d > 0) { i0 = csr_src[p]; e0 = ew[p]; }
    if (d > 1) { i1 = csr_src[p + 1]; e1 = ew[p + 1]; }
    int rem = d;
    while (rem > 0) {
        int n0 = 0, n1 = 0;
        float f0 = 0.f, f1 = 0.f;
        if (rem > 2) { n0 = csr_src[p + 2]; f0 = ew[p + 2]; }
        if (rem > 3) { n1 = csr_src[p + 3]; f1 = ew[p + 3]; }
        uint2 g0 = hu2[(size_t)i0 * 16 + j];
        uint2 g1 = hu2[(size_t)i1 * 16 + j];   // rem==1: i1=0,e1=0 -> adds 0
        a0 = fmaf(e0, __uint_as_float(g0.x << 16), a0);
        a1 = fmaf(e0, __uint_as_float(g0.x & 0xffff0000u), a1);
        a2 = fmaf(e0, __uint_as_float(g0.y << 16), a2);
        a3 = fmaf(e0, __uint_as_float(g0.y & 0xffff0000u), a3);
        a0 = fmaf(e1, __uint_as_float(g1.x << 16), a0);
        a1 = fmaf(e1, __uint_as_float(g1.x & 0xffff0000u), a1);
        a2 = fmaf(e1, __uint_as_float(g1.y << 16), a2);
        a3 = fmaf(e1, __uint_as_float(g1.y & 0xffff0000u), a3);
        i0 = n0; e0 = f0; i1 = n1; e1 = f1;
        p += 2; rem -= 2;
    }
    return make_float4(fmaxf(a0, 0.f), fmaxf(a1, 0.f), fmaxf(a2, 0.f), fmaxf(a3, 0.f));
}

// ---------------- fused: x = relu(agg(h_in)); h_out = x @ W + b ----------------
// 16 nodes/block (4 waves x 4 groups x 1 node); LDS 20KB

template <bool BF>
__device__ __forceinline__ void fuse_body(const int* row_start, const int* deg,
                                          const int* __restrict__ csr_src,
                                          const float* __restrict__ ew,
                                          const uint2* __restrict__ hu2,
                                          const void* W, int Woff, const void* b, int boff,
                                          unsigned short* h_out,
                                          float* Wl, float (*xs)[64]) {
    int t = threadIdx.x, w = t >> 6, lane = t & 63;
    for (int i = t; i < 64 * 64; i += 256) Wl[i] = LD<BF>(W, Woff + i);

    int g = lane >> 4, j = lane & 15;
    int idx = w * 4 + g;
    int v = blockIdx.x * 16 + idx;   // grid exact: 6250*16 = 100000
    float4 r = agg16(row_start[v], deg[v], csr_src, ew, hu2, j);
    *(float4*)&xs[idx][4 * j] = r;   // relu already applied
    __syncthreads();

    float bias = LD<BF>(b, boff + lane);
    float A0 = bias, A1 = bias, A2 = bias, A3 = bias;
    for (int k = 0; k < 64; k += 4) {
        float w0 = Wl[(k + 0) * 64 + lane];
        float w1 = Wl[(k + 1) * 64 + lane];
        float w2 = Wl[(k + 2) * 64 + lane];
        float w3 = Wl[(k + 3) * 64 + lane];
        float4 x0 = *(const float4*)&xs[w * 4 + 0][k];   // lane-uniform: LDS broadcast
        float4 x1 = *(const float4*)&xs[w * 4 + 1][k];
        float4 x2 = *(const float4*)&xs[w * 4 + 2][k];
        float4 x3 = *(const float4*)&xs[w * 4 + 3][k];
        A0 = fmaf(x0.x, w0, A0); A0 = fmaf(x0.y, w1, A0); A0 = fmaf(x0.z, w2, A0); A0 = fmaf(x0.w, w3, A0);
        A1 = fmaf(x1.x, w0, A1); A1 = fmaf(x1.y, w1, A1); A1 = fmaf(x1.z, w2, A1); A1 = fmaf(x1.w, w3, A1);
        A2 = fmaf(x2.x, w0, A2); A2 = fmaf(x2.y, w1, A2); A2 = fmaf(x2.z, w2, A2); A2 = fmaf(x2.w, w3, A2);
        A3 = fmaf(x3.x, w0, A3); A3 = fmaf(x3.y, w1, A3); A3 = fmaf(x3.z, w2, A3); A3 = fmaf(x3.w, w3, A3);
    }
    int v0 = blockIdx.x * 16 + w * 4;
    h_out[(size_t)(v0 + 0) * 64 + lane] = f2bf(A0);
    h_out[(size_t)(v0 + 1) * 64 + lane] = f2bf(A1);
    h_out[(size_t)(v0 + 2) * 64 + lane] = f2bf(A2);
    h_out[(size_t)(v0 + 3) * 64 + lane] = f2bf(A3);
}

__global__ void k_fuse(const int* __restrict__ flag,
                       const int* row_start, const int* deg,
                       const int* __restrict__ csr_src, const float* __restrict__ ew,
                       const void* hu,
                       const void* W, int Woff, const void* b, int boff,
                       unsigned short* h_out) {
    __shared__ float Wl[64 * 64];
    __shared__ float xs[16][64];
    if (*flag)
        fuse_body<true>(row_start, deg, csr_src, ew, (const uint2*)hu,
                        W, Woff, b, boff, h_out, Wl, xs);
    else
        fuse_body<false>(row_start, deg, csr_src, ew, (const uint2*)hu,
                         W, Woff, b, boff, h_out, Wl, xs);
}

// ---------------- fused final: x3 = relu(agg(h3)); heads -> out ---------------
// 16 nodes/block (4 waves x 4 groups); phases identical to r17

template <bool BF>
__device__ __forceinline__ void fuse_heads_body(
        const int* row_start, const int* deg,
        const int* __restrict__ csr_src, const float* __restrict__ ew,
        const uint2* __restrict__ hu2,
        const void* rh1w, const void* rh1b, const void* rh2w, const void* rh2b,
        const void* meanw, const void* meanb, const void* stdw, const void* stdb,
        const void* cls1w, const void* cls1b, const void* cls2w, const void* cls2b,
        void* __restrict__ out,
        float* s_rh1, float* s_cls1, float* s_rh2, float* s_cls2,
        float* s_rh1b, float* s_cls1b, float* s_rh2b, float* s_mw, float* s_sw,
        float* s_c2b, float* s_msb,
        float (*xs)[64], float (*r1)[32], float (*c1h)[32], float (*r2)[16]) {
    int t = threadIdx.x, w = t >> 6, lane = t & 63;
    for (int i = t; i < 2048; i += 256) { s_rh1[i] = LD<BF>(rh1w, i); s_cls1[i] = LD<BF>(cls1w, i); }
    for (int i = t; i < 512; i += 256) s_rh2[i] = LD<BF>(rh2w, i);
    if (t < 64) s_cls2[t] = LD<BF>(cls2w, t);
    if (t < 32) { s_rh1b[t] = LD<BF>(rh1b, t); s_cls1b[t] = LD<BF>(cls1b, t); }
    else if (t < 48) { int i = t - 32; s_rh2b[i] = LD<BF>(rh2b, i); s_mw[i] = LD<BF>(meanw, i); s_sw[i] = LD<BF>(stdw, i); }
    else if (t == 48) { s_msb[0] = LD<BF>(meanb, 0); s_msb[1] = LD<BF>(stdb, 0); }
    else if (t == 49) { s_c2b[0] = LD<BF>(cls2b, 0); s_c2b[1] = LD<BF>(cls2b, 1); }

    int g = lane >> 4, j = lane & 15;
    int idx0 = w * 4 + g;
    int v00 = blockIdx.x * 16;
    float4 r = agg16(row_start[v00 + idx0], deg[v00 + idx0], csr_src, ew, hu2, j);
    *(float4*)&xs[idx0][4 * j] = r;
    __syncthreads();

    #pragma unroll
    for (int n = 0; n < 4; n++) {
        int idx = w * 4 + n;
        int c = lane & 31;
        const float* Wp = (lane < 32) ? s_rh1 : s_cls1;
        float a = (lane < 32) ? s_rh1b[c] : s_cls1b[c];
        #pragma unroll 8
        for (int k = 0; k < 64; k++) a = fmaf(xs[idx][k], Wp[k * 32 + c], a);
        a = fmaxf(a, 0.f);
        if (lane < 32) r1[idx][c] = a; else c1h[idx][c] = a;
    }
    __syncthreads();

    #pragma unroll
    for (int n = 0; n < 4; n++) {
        int idx = w * 4 + n;
        if (lane < 16) {
            float a = s_rh2b[lane];
            #pragma unroll
            for (int k = 0; k < 32; k++) a = fmaf(r1[idx][k], s_rh2[k * 16 + lane], a);
            r2[idx][lane] = fmaxf(a, 0.f);
        }
    }
    __syncthreads();

    #pragma unroll
    for (int n = 0; n < 4; n++) {
        int idx = w * 4 + n;
        int v = v00 + idx;
        if (lane == 0) {
            float m = s_msb[0];
            #pragma unroll
            for (int k = 0; k < 16; k++) m = fmaf(r2[idx][k], s_mw[k], m);
            if (BF) ((unsigned short*)out)[v] = f2bf(m); else ((float*)out)[v] = m;
        } else if (lane == 1) {
            float sv = s_msb[1];
            #pragma unroll
            for (int k = 0; k < 16; k++) sv = fmaf(r2[idx][k], s_sw[k], sv);
            float sp = fmaxf(sv, 0.f) + log1pf(expf(-fabsf(sv)));   // stable softplus
            if (BF) ((unsigned short*)out)[N_NODES + v] = f2bf(sp); else ((float*)out)[N_NODES + v] = sp;
        } else if (lane < 4) {
            int jj = lane - 2;
            float a = s_c2b[jj];
            #pragma unroll
            for (int k = 0; k < 32; k++) a = fmaf(c1h[idx][k], s_cls2[k * 2 + jj], a);
            size_t pos = (size_t)2 * N_NODES + (size_t)v * 2 + jj;
            if (BF) ((unsigned short*)out)[pos] = f2bf(a); else ((float*)out)[pos] = a;
        }
    }
}

__global__ void k_fuse_heads(const int* __restrict__ flag,
                             const int* row_start, const int* deg,
                             const int* __restrict__ csr_src, const float* __restrict__ ew,
                             const void* hu,
                             const void* rh1w, const void* rh1b, const void* rh2w, const void* rh2b,
                             const void* meanw, const void* meanb, const void* stdw, const void* stdb,
                             const void* cls1w, const void* cls1b, const void* cls2w, const void* cls2b,
                             void* out) {
    __shared__ float s_rh1[64 * 32], s_cls1[64 * 32], s_rh2[32 * 16], s_cls2[32 * 2];
    __shared__ float s_rh1b[32], s_cls1b[32], s_rh2b[16], s_mw[16], s_sw[16], s_c2b[2], s_msb[2];
    __shared__ float xs[16][64], r1[16][32], c1h[16][32], r2[16][16];
    if (*flag)
        fuse_heads_body<true>(row_start, deg, csr_src, ew, (const uint2*)hu,
                              rh1w, rh1b, rh2w, rh2b, meanw, meanb, stdw, stdb,
                              cls1w, cls1b, cls2w, cls2b, out,
                              s_rh1, s_cls1, s_rh2, s_cls2, s_rh1b, s_cls1b, s_rh2b,
                              s_mw, s_sw, s_c2b, s_msb, xs, r1, c1h, r2);
    else
        fuse_heads_body<false>(row_start, deg, csr_src, ew, (const uint2*)hu,
                               rh1w, rh1b, rh2w, rh2b, meanw, meanb, stdw, stdb,
                               cls1w, cls1b, cls2w, cls2b, out,
                               s_rh1, s_cls1, s_rh2, s_cls2, s_rh1b, s_cls1b, s_rh2b,
                               s_mw, s_sw, s_c2b, s_msb, xs, r1, c1h, r2);
}

// ---------------- launch ----------------

extern "C" void kernel_launch(void* const* d_in, const int* in_sizes, int n_in,
                              void* d_out, int out_size, void* d_ws, size_t ws_size,
                              hipStream_t stream) {
    const void* x_in  = d_in[0];
    const int* ei     = (const int*)d_in[1];
    const void* ea    = d_in[2];
    const void* W0    = d_in[3];
    const void* b0    = d_in[4];
    const void* Ws    = d_in[5];
    const void* bs    = d_in[6];
    const void* ew1   = d_in[7];
    const void* eb1   = d_in[8];
    const void* ew2   = d_in[9];
    const void* eb2   = d_in[10];
    const void* rh1w  = d_in[11];
    const void* rh1b  = d_in[12];
    const void* rh2w  = d_in[13];
    const void* rh2b  = d_in[14];
    const void* meanw = d_in[15];
    const void* meanb = d_in[16];
    const void* stdw  = d_in[17];
    const void* stdb  = d_in[18];
    const void* cls1w = d_in[19];
    const void* cls1b = d_in[20];
    const void* cls2w = d_in[21];
    const void* cls2b = d_in[22];

    char* wsp = (char*)d_ws;
    auto alloc = [&](size_t bytes) -> char* {
        char* p = wsp;
        wsp += (bytes + 255) & ~(size_t)255;
        return p;
    };
    // footprint ~59 MB (< 78.2 MB proven):
    //   csr_edge (25.6 MB) is dead after k_ew -> aliased with hA+hB (12.8+12.8)
    int* flag       = (int*)alloc(4);
    int* deg        = (int*)alloc((size_t)N_NODES * 4);
    int* row_start  = (int*)alloc((size_t)N_NODES * 4);
    int* cursor     = (int*)alloc((size_t)N_NODES * 4);
    int* bsum       = (int*)alloc((size_t)NB_SCAN * 4);
    int* boff       = (int*)alloc((size_t)NB_SCAN * 4);
    int* csr_src    = (int*)alloc((size_t)N_EDGES * 4);
    float* ew4      = (float*)alloc((size_t)4 * N_EDGES * 4);
    char* hreg      = alloc((size_t)N_EDGES * 16);       // union region, 25.6 MB
    uint4* csr_edge = (uint4*)hreg;
    unsigned short* hA = (unsigned short*)hreg;
    unsigned short* hB = (unsigned short*)(hreg + (size_t)N_NODES * 64 * 2);

    k_detect<<<1, 256, 0, stream>>>((const unsigned*)x_in, flag);
    hipMemsetAsync(deg, 0, (size_t)N_NODES * 4, stream);
    k_hist<<<6250, 256, 0, stream>>>(ei, deg);
    k_scan_partial<<<NB_SCAN, 256, 0, stream>>>(deg, bsum);
    k_scan_mid<<<1, 512, 0, stream>>>(bsum, boff);
    k_scan_final<<<NB_SCAN, 256, 0, stream>>>(deg, boff, row_start, cursor);
    k_scatter<<<6250, 256, 0, stream>>>(flag, ei, ea, cursor, csr_edge);
    k_ew<<<6250, 256, 0, stream>>>(flag, csr_edge, ew1, eb1, ew2, eb2, csr_src, ew4);

    // h0 = x_in @ W0 + b0   (hA clobbers csr_edge region -- dead after k_ew)
    k_dense0<<<6250, 256, 0, stream>>>(flag, x_in, W0, b0, hA);

    unsigned short* hin = hA;
    unsigned short* hout = hB;
    for (int l = 0; l < 3; l++) {
        k_fuse<<<6250, 256, 0, stream>>>(flag, row_start, deg, csr_src,
                                         ew4 + (size_t)l * N_EDGES, hin,
                                         Ws, l * 64 * 64, bs, l * 64, hout);
        unsigned short* tmp = hin; hin = hout; hout = tmp;
    }
    k_fuse_heads<<<6250, 256, 0, stream>>>(flag, row_start, deg, csr_src,
                                           ew4 + (size_t)3 * N_EDGES, hin,
                                           rh1w, rh1b, rh2w, rh2b, meanw, meanb,
                                           stdw, stdb, cls1w, cls1b, cls2w, cls2b,
                                           d_out);
}

// Round 6
// 596.117 us; speedup vs baseline: 1.1758x; 1.0005x over previous
//
#include <hip/hip_runtime.h>
#include <stdint.h>

#define N_NODES 100000
#define N_EDGES 1600000
#define NB_SCAN 391   // ceil(N_NODES/256)

// Round 21 (= r20 with compile fix). r19: 596 us (best). k_scatter 112us,
// WRITE=101MB = 1.6M x 64B dirty-line bounces. Agg: VALUBusy 65%, occ 49%,
// latency-bound at gather depth 1.
// Changes vs r19: (1) k_scatter nontemporal 16B store via clang
// ext_vector_type(4) (HIP uint4 class rejected by the builtin). (2) agg16
// unrolled to 4 edges/iter with depth-1 prefetch of next quad -> 4 gathers
// in flight per group. idx=0/e=0 padding adds exact 0. Same fp32 math/order
// -> absmax unchanged. Everything else r19-verbatim.

typedef unsigned int nt_uint4 __attribute__((ext_vector_type(4)));

__device__ __forceinline__ float bf2f(unsigned short s) {
    return __uint_as_float(((unsigned)s) << 16);
}
__device__ __forceinline__ unsigned short f2bf(float f) {
    unsigned u = __float_as_uint(f);
    u += 0x7fffu + ((u >> 16) & 1u);
    return (unsigned short)(u >> 16);
}
template <bool BF16>
__device__ __forceinline__ float LD(const void* p, size_t i) {
    if (BF16) return bf2f(((const unsigned short*)p)[i]);
    return ((const float*)p)[i];
}

// ---------------- dtype detection (proven) ----------------
__global__ void k_detect(const unsigned* __restrict__ xw, int* __restrict__ flag) {
    __shared__ int tot;
    if (threadIdx.x == 0) tot = 0;
    __syncthreads();
    int hit = 0;
    for (int i = threadIdx.x; i < 1024; i += 256) {
        unsigned e = (xw[i] >> 7) & 0xFFu;
        if (e >= 110u && e <= 135u) hit++;
    }
    atomicAdd(&tot, hit);
    __syncthreads();
    if (threadIdx.x == 0) *flag = (tot >= 512) ? 1 : 0;
}

// ---------------- CSR build ----------------

__global__ void k_hist(const int* __restrict__ ei, int* __restrict__ deg) {
    int e = blockIdx.x * 256 + threadIdx.x;
    if (e < N_EDGES) atomicAdd(&deg[ei[N_EDGES + e]], 1);
}

__global__ void k_scan_partial(const int* __restrict__ deg, int* __restrict__ bsum) {
    int t = threadIdx.x;
    int i = blockIdx.x * 256 + t;
    int v = (i < N_NODES) ? deg[i] : 0;
    for (int off = 32; off > 0; off >>= 1) v += __shfl_down(v, off, 64);
    __shared__ int ws4[4];
    if ((t & 63) == 0) ws4[t >> 6] = v;
    __syncthreads();
    if (t == 0) bsum[blockIdx.x] = ws4[0] + ws4[1] + ws4[2] + ws4[3];
}

__global__ void k_scan_mid(const int* __restrict__ bsum, int* __restrict__ boff) {
    __shared__ int s[512];
    int t = threadIdx.x;
    int v = (t < NB_SCAN) ? bsum[t] : 0;
    s[t] = v;
    __syncthreads();
    for (int off = 1; off < 512; off <<= 1) {
        int x = (t >= off) ? s[t - off] : 0;
        __syncthreads();
        s[t] += x;
        __syncthreads();
    }
    if (t < NB_SCAN) boff[t] = s[t] - v;   // exclusive
}

__global__ void k_scan_final(const int* __restrict__ deg, const int* __restrict__ boff,
                             int* __restrict__ row_start, int* __restrict__ cursor) {
    __shared__ int s[256];
    int t = threadIdx.x;
    int i = blockIdx.x * 256 + t;
    int v = (i < N_NODES) ? deg[i] : 0;
    s[t] = v;
    __syncthreads();
    for (int off = 1; off < 256; off <<= 1) {
        int x = (t >= off) ? s[t - off] : 0;
        __syncthreads();
        s[t] += x;
        __syncthreads();
    }
    if (i < N_NODES) {
        int rs = boff[blockIdx.x] + s[t] - v;
        row_start[i] = rs;
        cursor[i] = rs;
    }
}

// ---------------- CSR scatter: ONE 16B packed nontemporal write per edge ----

template <bool BF>
__device__ __forceinline__ void scatter_body(const int* __restrict__ ei,
                                             const void* __restrict__ ea,
                                             int* __restrict__ cursor,
                                             uint4* __restrict__ csr_edge) {
    int e = blockIdx.x * 256 + threadIdx.x;   // grid exact: 6250*256 = 1.6M
    int s = ei[e];
    int d = ei[N_EDGES + e];
    float a0 = LD<BF>(ea, (size_t)e * 2);
    float a1 = LD<BF>(ea, (size_t)e * 2 + 1);
    int slot = atomicAdd(&cursor[d], 1);
    nt_uint4 val;
    val.x = (unsigned)s;
    val.y = __float_as_uint(a0);
    val.z = __float_as_uint(a1);
    val.w = 0u;
    __builtin_nontemporal_store(val, (nt_uint4*)&csr_edge[slot]);
}

__global__ void k_scatter(const int* __restrict__ flag, const int* ei, const void* ea,
                          int* cursor, uint4* csr_edge) {
    if (*flag) scatter_body<true>(ei, ea, cursor, csr_edge);
    else       scatter_body<false>(ei, ea, cursor, csr_edge);
}

// ---------------- edge-MLP pass: slot-ordered, fully coalesced ----------------

template <bool BF>
__device__ __forceinline__ void ew_body(const uint4* __restrict__ csr_edge,
                                        const void* ew1, const void* eb1,
                                        const void* ew2, const void* eb2,
                                        int* __restrict__ csr_src,
                                        float* __restrict__ ew4,
                                        float (*w1)[2][16], float (*b1)[16],
                                        float (*w2)[16], float* b2) {
    int t = threadIdx.x;
    if (t < 128) ((float*)w1)[t] = LD<BF>(ew1, t);
    else if (t < 192) ((float*)b1)[t - 128] = LD<BF>(eb1, t - 128);
    else ((float*)w2)[t - 192] = LD<BF>(ew2, t - 192);
    if (t < 4) b2[t] = LD<BF>(eb2, t);
    __syncthreads();

    int e = blockIdx.x * 256 + t;   // grid exact: 6250*256 = 1.6M
    uint4 u = csr_edge[e];
    csr_src[e] = (int)u.x;
    float a0 = __uint_as_float(u.y);
    float a1 = __uint_as_float(u.z);
    #pragma unroll
    for (int l = 0; l < 4; l++) {
        float z = b2[l];
        #pragma unroll
        for (int q = 0; q < 16; q++) {
            float hj = fmaf(a0, w1[l][0][q], fmaf(a1, w1[l][1][q], b1[l][q]));
            z = fmaf(fmaxf(hj, 0.f), w2[l][q], z);
        }
        ew4[(size_t)l * N_EDGES + e] = 1.f / (1.f + expf(-z));
    }
}

__global__ void k_ew(const int* __restrict__ flag, const uint4* __restrict__ csr_edge,
                     const void* ew1, const void* eb1, const void* ew2, const void* eb2,
                     int* csr_src, float* ew4) {
    __shared__ float w1[4][2][16], b1[4][16], w2[4][16], b2[4];
    if (*flag) ew_body<true>(csr_edge, ew1, eb1, ew2, eb2, csr_src, ew4, w1, b1, w2, b2);
    else       ew_body<false>(csr_edge, ew1, eb1, ew2, eb2, csr_src, ew4, w1, b1, w2, b2);
}

// ---------------- layer 0 dense ----------------

template <bool BF>
__device__ __forceinline__ void dense0_body(const void* __restrict__ x,
                                            const void* __restrict__ W,
                                            const void* __restrict__ b,
                                            unsigned short* __restrict__ h,
                                            float* Wl, float (*xl)[32]) {
    int t = threadIdx.x, w = t >> 6, lane = t & 63;
    for (int i = t; i < 32 * 64; i += 256) Wl[i] = LD<BF>(W, i);
    int v0 = blockIdx.x * 16 + w * 4;
    if (lane < 32) {
        #pragma unroll
        for (int n = 0; n < 4; n++)
            xl[w * 4 + n][lane] = LD<BF>(x, (size_t)(v0 + n) * 32 + lane);
    }
    __syncthreads();
    float bias = LD<BF>(b, lane);
    float a0 = bias, a1 = bias, a2 = bias, a3 = bias;
    #pragma unroll 8
    for (int k = 0; k < 32; k++) {
        float wv = Wl[k * 64 + lane];
        a0 = fmaf(xl[w * 4 + 0][k], wv, a0);
        a1 = fmaf(xl[w * 4 + 1][k], wv, a1);
        a2 = fmaf(xl[w * 4 + 2][k], wv, a2);
        a3 = fmaf(xl[w * 4 + 3][k], wv, a3);
    }
    h[(size_t)(v0 + 0) * 64 + lane] = f2bf(a0);
    h[(size_t)(v0 + 1) * 64 + lane] = f2bf(a1);
    h[(size_t)(v0 + 2) * 64 + lane] = f2bf(a2);
    h[(size_t)(v0 + 3) * 64 + lane] = f2bf(a3);
}

__global__ void k_dense0(const int* __restrict__ flag, const void* x, const void* W,
                         const void* b, unsigned short* h) {
    __shared__ float Wl[32 * 64];
    __shared__ float xl[16][32];
    if (*flag) dense0_body<true>(x, W, b, h, Wl, xl);
    else       dense0_body<false>(x, W, b, h, Wl, xl);
}

// ---------------- aggregation: 16 lanes/node, 4 edges/iter, per-lane acc ----
// h rows = 64 bf16 = 16 uint2. Group of 16 lanes owns one node; lane j owns
// channel quad 4j..4j+3 (one uint2 gather; group reads 128B/row contiguous).
// Scalar per-lane accumulators across all edges -> no butterfly, no shfl.
// 4 edges per iteration (4 gathers in flight), next quad prefetched.
// Out-of-range edges use idx=0/e=0 -> adds exact 0 (row 0 stays L2-hot).

__device__ __forceinline__ float4 agg16(int p, int d,
                                        const int* __restrict__ csr_src,
                                        const float* __restrict__ ew,
                                        const uint2* __restrict__ hu2,
                                        int j) {
    float a0 = 0.f, a1 = 0.f, a2 = 0.f, a3 = 0.f;
    int i0 = 0, i1 = 0, i2 = 0, i3 = 0;
    float e0 = 0.f, e1 = 0.f, e2 = 0.f, e3 = 0.f;
    if (d > 0) { i0 = csr_src[p];     e0 = ew[p]; }
    if (d > 1) { i1 = csr_src[p + 1]; e1 = ew[p + 1]; }
    if (d > 2) { i2 = csr_src[p + 2]; e2 = ew[p + 2]; }
    if (d > 3) { i3 = csr_src[p + 3]; e3 = ew[p + 3]; }
    int rem = d;
    while (rem > 0) {
        int n0 = 0, n1 = 0, n2 = 0, n3 = 0;
        float f0 = 0.f, f1 = 0.f, f2 = 0.f, f3 = 0.f;
        if (rem > 4) { n0 = csr_src[p + 4]; f0 = ew[p + 4]; }
        if (rem > 5) { n1 = csr_src[p + 5]; f1 = ew[p + 5]; }
        if (rem > 6) { n2 = csr_src[p + 6]; f2 = ew[p + 6]; }
        if (rem > 7) { n3 = csr_src[p + 7]; f3 = ew[p + 7]; }
        uint2 g0 = hu2[(size_t)i0 * 16 + j];
        uint2 g1 = hu2[(size_t)i1 * 16 + j];
        uint2 g2 = hu2[(size_t)i2 * 16 + j];
        uint2 g3 = hu2[(size_t)i3 * 16 + j];
        a0 = fmaf(e0, __uint_as_float(g0.x << 16), a0);
        a1 = fmaf(e0, __uint_as_float(g0.x & 0xffff0000u), a1);
        a2 = fmaf(e0, __uint_as_float(g0.y << 16), a2);
        a3 = fmaf(e0, __uint_as_float(g0.y & 0xffff0000u), a3);
        a0 = fmaf(e1, __uint_as_float(g1.x << 16), a0);
        a1 = fmaf(e1, __uint_as_float(g1.x & 0xffff0000u), a1);
        a2 = fmaf(e1, __uint_as_float(g1.y << 16), a2);
        a3 = fmaf(e1, __uint_as_float(g1.y & 0xffff0000u), a3);
        a0 = fmaf(e2, __uint_as_float(g2.x << 16), a0);
        a1 = fmaf(e2, __uint_as_float(g2.x & 0xffff0000u), a1);
        a2 = fmaf(e2, __uint_as_float(g2.y << 16), a2);
        a3 = fmaf(e2, __uint_as_float(g2.y & 0xffff0000u), a3);
        a0 = fmaf(e3, __uint_as_float(g3.x << 16), a0);
        a1 = fmaf(e3, __uint_as_float(g3.x & 0xffff0000u), a1);
        a2 = fmaf(e3, __uint_as_float(g3.y << 16), a2);
        a3 = fmaf(e3, __uint_as_float(g3.y & 0xffff0000u), a3);
        i0 = n0; e0 = f0; i1 = n1; e1 = f1;
        i2 = n2; e2 = f2; i3 = n3; e3 = f3;
        p += 4; rem -= 4;
    }
    return make_float4(fmaxf(a0, 0.f), fmaxf(a1, 0.f), fmaxf(a2, 0.f), fmaxf(a3, 0.f));
}

// ---------------- fused: x = relu(agg(h_in)); h_out = x @ W + b ----------------
// 16 nodes/block (4 waves x 4 groups x 1 node); LDS 20KB

template <bool BF>
__device__ __forceinline__ void fuse_body(const int* row_start, const int* deg,
                                          const int* __restrict__ csr_src,
                                          const float* __restrict__ ew,
                                          const uint2* __restrict__ hu2,
                                          const void* W, int Woff, const void* b, int boff,
                                          unsigned short* h_out,
                                          float* Wl, float (*xs)[64]) {
    int t = threadIdx.x, w = t >> 6, lane = t & 63;
    for (int i = t; i < 64 * 64; i += 256) Wl[i] = LD<BF>(W, Woff + i);

    int g = lane >> 4, j = lane & 15;
    int idx = w * 4 + g;
    int v = blockIdx.x * 16 + idx;   // grid exact: 6250*16 = 100000
    float4 r = agg16(row_start[v], deg[v], csr_src, ew, hu2, j);
    *(float4*)&xs[idx][4 * j] = r;   // relu already applied
    __syncthreads();

    float bias = LD<BF>(b, boff + lane);
    float A0 = bias, A1 = bias, A2 = bias, A3 = bias;
    for (int k = 0; k < 64; k += 4) {
        float w0 = Wl[(k + 0) * 64 + lane];
        float w1 = Wl[(k + 1) * 64 + lane];
        float w2 = Wl[(k + 2) * 64 + lane];
        float w3 = Wl[(k + 3) * 64 + lane];
        float4 x0 = *(const float4*)&xs[w * 4 + 0][k];   // lane-uniform: LDS broadcast
        float4 x1 = *(const float4*)&xs[w * 4 + 1][k];
        float4 x2 = *(const float4*)&xs[w * 4 + 2][k];
        float4 x3 = *(const float4*)&xs[w * 4 + 3][k];
        A0 = fmaf(x0.x, w0, A0); A0 = fmaf(x0.y, w1, A0); A0 = fmaf(x0.z, w2, A0); A0 = fmaf(x0.w, w3, A0);
        A1 = fmaf(x1.x, w0, A1); A1 = fmaf(x1.y, w1, A1); A1 = fmaf(x1.z, w2, A1); A1 = fmaf(x1.w, w3, A1);
        A2 = fmaf(x2.x, w0, A2); A2 = fmaf(x2.y, w1, A2); A2 = fmaf(x2.z, w2, A2); A2 = fmaf(x2.w, w3, A2);
        A3 = fmaf(x3.x, w0, A3); A3 = fmaf(x3.y, w1, A3); A3 = fmaf(x3.z, w2, A3); A3 = fmaf(x3.w, w3, A3);
    }
    int v0 = blockIdx.x * 16 + w * 4;
    h_out[(size_t)(v0 + 0) * 64 + lane] = f2bf(A0);
    h_out[(size_t)(v0 + 1) * 64 + lane] = f2bf(A1);
    h_out[(size_t)(v0 + 2) * 64 + lane] = f2bf(A2);
    h_out[(size_t)(v0 + 3) * 64 + lane] = f2bf(A3);
}

__global__ void k_fuse(const int* __restrict__ flag,
                       const int* row_start, const int* deg,
                       const int* __restrict__ csr_src, const float* __restrict__ ew,
                       const void* hu,
                       const void* W, int Woff, const void* b, int boff,
                       unsigned short* h_out) {
    __shared__ float Wl[64 * 64];
    __shared__ float xs[16][64];
    if (*flag)
        fuse_body<true>(row_start, deg, csr_src, ew, (const uint2*)hu,
                        W, Woff, b, boff, h_out, Wl, xs);
    else
        fuse_body<false>(row_start, deg, csr_src, ew, (const uint2*)hu,
                         W, Woff, b, boff, h_out, Wl, xs);
}

// ---------------- fused final: x3 = relu(agg(h3)); heads -> out ---------------
// 16 nodes/block (4 waves x 4 groups); phases identical to r19

template <bool BF>
__device__ __forceinline__ void fuse_heads_body(
        const int* row_start, const int* deg,
        const int* __restrict__ csr_src, const float* __restrict__ ew,
        const uint2* __restrict__ hu2,
        const void* rh1w, const void* rh1b, const void* rh2w, const void* rh2b,
        const void* meanw, const void* meanb, const void* stdw, const void* stdb,
        const void* cls1w, const void* cls1b, const void* cls2w, const void* cls2b,
        void* __restrict__ out,
        float* s_rh1, float* s_cls1, float* s_rh2, float* s_cls2,
        float* s_rh1b, float* s_cls1b, float* s_rh2b, float* s_mw, float* s_sw,
        float* s_c2b, float* s_msb,
        float (*xs)[64], float (*r1)[32], float (*c1h)[32], float (*r2)[16]) {
    int t = threadIdx.x, w = t >> 6, lane = t & 63;
    for (int i = t; i < 2048; i += 256) { s_rh1[i] = LD<BF>(rh1w, i); s_cls1[i] = LD<BF>(cls1w, i); }
    for (int i = t; i < 512; i += 256) s_rh2[i] = LD<BF>(rh2w, i);
    if (t < 64) s_cls2[t] = LD<BF>(cls2w, t);
    if (t < 32) { s_rh1b[t] = LD<BF>(rh1b, t); s_cls1b[t] = LD<BF>(cls1b, t); }
    else if (t < 48) { int i = t - 32; s_rh2b[i] = LD<BF>(rh2b, i); s_mw[i] = LD<BF>(meanw, i); s_sw[i] = LD<BF>(stdw, i); }
    else if (t == 48) { s_msb[0] = LD<BF>(meanb, 0); s_msb[1] = LD<BF>(stdb, 0); }
    else if (t == 49) { s_c2b[0] = LD<BF>(cls2b, 0); s_c2b[1] = LD<BF>(cls2b, 1); }

    int g = lane >> 4, j = lane & 15;
    int idx0 = w * 4 + g;
    int v00 = blockIdx.x * 16;
    float4 r = agg16(row_start[v00 + idx0], deg[v00 + idx0], csr_src, ew, hu2, j);
    *(float4*)&xs[idx0][4 * j] = r;
    __syncthreads();

    #pragma unroll
    for (int n = 0; n < 4; n++) {
        int idx = w * 4 + n;
        int c = lane & 31;
        const float* Wp = (lane < 32) ? s_rh1 : s_cls1;
        float a = (lane < 32) ? s_rh1b[c] : s_cls1b[c];
        #pragma unroll 8
        for (int k = 0; k < 64; k++) a = fmaf(xs[idx][k], Wp[k * 32 + c], a);
        a = fmaxf(a, 0.f);
        if (lane < 32) r1[idx][c] = a; else c1h[idx][c] = a;
    }
    __syncthreads();

    #pragma unroll
    for (int n = 0; n < 4; n++) {
        int idx = w * 4 + n;
        if (lane < 16) {
            float a = s_rh2b[lane];
            #pragma unroll
            for (int k = 0; k < 32; k++) a = fmaf(r1[idx][k], s_rh2[k * 16 + lane], a);
            r2[idx][lane] = fmaxf(a, 0.f);
        }
    }
    __syncthreads();

    #pragma unroll
    for (int n = 0; n < 4; n++) {
        int idx = w * 4 + n;
        int v = v00 + idx;
        if (lane == 0) {
            float m = s_msb[0];
            #pragma unroll
            for (int k = 0; k < 16; k++) m = fmaf(r2[idx][k], s_mw[k], m);
            if (BF) ((unsigned short*)out)[v] = f2bf(m); else ((float*)out)[v] = m;
        } else if (lane == 1) {
            float sv = s_msb[1];
            #pragma unroll
            for (int k = 0; k < 16; k++) sv = fmaf(r2[idx][k], s_sw[k], sv);
            float sp = fmaxf(sv, 0.f) + log1pf(expf(-fabsf(sv)));   // stable softplus
            if (BF) ((unsigned short*)out)[N_NODES + v] = f2bf(sp); else ((float*)out)[N_NODES + v] = sp;
        } else if (lane < 4) {
            int jj = lane - 2;
            float a = s_c2b[jj];
            #pragma unroll
            for (int k = 0; k < 32; k++) a = fmaf(c1h[idx][k], s_cls2[k * 2 + jj], a);
            size_t pos = (size_t)2 * N_NODES + (size_t)v * 2 + jj;
            if (BF) ((unsigned short*)out)[pos] = f2bf(a); else ((float*)out)[pos] = a;
        }
    }
}

__global__ void k_fuse_heads(const int* __restrict__ flag,
                             const int* row_start, const int* deg,
                             const int* __restrict__ csr_src, const float* __restrict__ ew,
                             const void* hu,
                             const void* rh1w, const void* rh1b, const void* rh2w, const void* rh2b,
                             const void* meanw, const void* meanb, const void* stdw, const void* stdb,
                             const void* cls1w, const void* cls1b, const void* cls2w, const void* cls2b,
                             void* out) {
    __shared__ float s_rh1[64 * 32], s_cls1[64 * 32], s_rh2[32 * 16], s_cls2[32 * 2];
    __shared__ float s_rh1b[32], s_cls1b[32], s_rh2b[16], s_mw[16], s_sw[16], s_c2b[2], s_msb[2];
    __shared__ float xs[16][64], r1[16][32], c1h[16][32], r2[16][16];
    if (*flag)
        fuse_heads_body<true>(row_start, deg, csr_src, ew, (const uint2*)hu,
                              rh1w, rh1b, rh2w, rh2b, meanw, meanb, stdw, stdb,
                              cls1w, cls1b, cls2w, cls2b, out,
                              s_rh1, s_cls1, s_rh2, s_cls2, s_rh1b, s_cls1b, s_rh2b,
                              s_mw, s_sw, s_c2b, s_msb, xs, r1, c1h, r2);
    else
        fuse_heads_body<false>(row_start, deg, csr_src, ew, (const uint2*)hu,
                               rh1w, rh1b, rh2w, rh2b, meanw, meanb, stdw, stdb,
                               cls1w, cls1b, cls2w, cls2b, out,
                               s_rh1, s_cls1, s_rh2, s_cls2, s_rh1b, s_cls1b, s_rh2b,
                               s_mw, s_sw, s_c2b, s_msb, xs, r1, c1h, r2);
}

// ---------------- launch ----------------

extern "C" void kernel_launch(void* const* d_in, const int* in_sizes, int n_in,
                              void* d_out, int out_size, void* d_ws, size_t ws_size,
                              hipStream_t stream) {
    const void* x_in  = d_in[0];
    const int* ei     = (const int*)d_in[1];
    const void* ea    = d_in[2];
    const void* W0    = d_in[3];
    const void* b0    = d_in[4];
    const void* Ws    = d_in[5];
    const void* bs    = d_in[6];
    const void* ew1   = d_in[7];
    const void* eb1   = d_in[8];
    const void* ew2   = d_in[9];
    const void* eb2   = d_in[10];
    const void* rh1w  = d_in[11];
    const void* rh1b  = d_in[12];
    const void* rh2w  = d_in[13];
    const void* rh2b  = d_in[14];
    const void* meanw = d_in[15];
    const void* meanb = d_in[16];
    const void* stdw  = d_in[17];
    const void* stdb  = d_in[18];
    const void* cls1w = d_in[19];
    const void* cls1b = d_in[20];
    const void* cls2w = d_in[21];
    const void* cls2b = d_in[22];

    char* wsp = (char*)d_ws;
    auto alloc = [&](size_t bytes) -> char* {
        char* p = wsp;
        wsp += (bytes + 255) & ~(size_t)255;
        return p;
    };
    // footprint ~59 MB (< 78.2 MB proven):
    //   csr_edge (25.6 MB) is dead after k_ew -> aliased with hA+hB (12.8+12.8)
    int* flag       = (int*)alloc(4);
    int* deg        = (int*)alloc((size_t)N_NODES * 4);
    int* row_start  = (int*)alloc((size_t)N_NODES * 4);
    int* cursor     = (int*)alloc((size_t)N_NODES * 4);
    int* bsum       = (int*)alloc((size_t)NB_SCAN * 4);
    int* boff       = (int*)alloc((size_t)NB_SCAN * 4);
    int* csr_src    = (int*)alloc((size_t)N_EDGES * 4);
    float* ew4      = (float*)alloc((size_t)4 * N_EDGES * 4);
    char* hreg      = alloc((size_t)N_EDGES * 16);       // union region, 25.6 MB
    uint4* csr_edge = (uint4*)hreg;
    unsigned short* hA = (unsigned short*)hreg;
    unsigned short* hB = (unsigned short*)(hreg + (size_t)N_NODES * 64 * 2);

    k_detect<<<1, 256, 0, stream>>>((const unsigned*)x_in, flag);
    hipMemsetAsync(deg, 0, (size_t)N_NODES * 4, stream);
    k_hist<<<6250, 256, 0, stream>>>(ei, deg);
    k_scan_partial<<<NB_SCAN, 256, 0, stream>>>(deg, bsum);
    k_scan_mid<<<1, 512, 0, stream>>>(bsum, boff);
    k_scan_final<<<NB_SCAN, 256, 0, stream>>>(deg, boff, row_start, cursor);
    k_scatter<<<6250, 256, 0, stream>>>(flag, ei, ea, cursor, csr_edge);
    k_ew<<<6250, 256, 0, stream>>>(flag, csr_edge, ew1, eb1, ew2, eb2, csr_src, ew4);

    // h0 = x_in @ W0 + b0   (hA clobbers csr_edge region -- dead after k_ew)
    k_dense0<<<6250, 256, 0, stream>>>(flag, x_in, W0, b0, hA);

    unsigned short* hin = hA;
    unsigned short* hout = hB;
    for (int l = 0; l < 3; l++) {
        k_fuse<<<6250, 256, 0, stream>>>(flag, row_start, deg, csr_src,
                                         ew4 + (size_t)l * N_EDGES, hin,
                                         Ws, l * 64 * 64, bs, l * 64, hout);
        unsigned short* tmp = hin; hin = hout; hout = tmp;
    }
    k_fuse_heads<<<6250, 256, 0, stream>>>(flag, row_start, deg, csr_src,
                                           ew4 + (size_t)3 * N_EDGES, hin,
                                           rh1w, rh1b, rh2w, rh2b, meanw, meanb,
                                           stdw, stdb, cls1w, cls1b, cls2w, cls2b,
                                           d_out);
}